// Round 16
// baseline (202.829 us; speedup 1.0000x reference)
//
#include <hip/hip_runtime.h>
#include <hip/hip_bf16.h>

typedef _Float16 f16;
typedef _Float16 half8 __attribute__((ext_vector_type(8)));
typedef _Float16 half4_t __attribute__((ext_vector_type(4)));
typedef float floatx16 __attribute__((ext_vector_type(16)));

__device__ __forceinline__ void gll16(const void* g, void* l) {
    __builtin_amdgcn_global_load_lds(
        (const __attribute__((address_space(1))) void*)g,
        (__attribute__((address_space(3))) void*)l, 16, 0, 0);
}

// ============================================================
// Kernel 1: fused MLP bank + h_in GEMM. grid 64, 128 thr.
// Each block redundantly computes all 16 embeddings (cheap),
// then its 128-wide j-slice of h_in = e @ hyp_w2 + hyp_b2.
// ============================================================
__global__ __launch_bounds__(128) void embed_ab(
    const float* __restrict__ seidel,
    const float* __restrict__ m1W1, const float* __restrict__ m1b1,
    const float* __restrict__ m1W2, const float* __restrict__ m1b2,
    const float* __restrict__ m2W1, const float* __restrict__ m2b1,
    const float* __restrict__ m2W2, const float* __restrict__ m2b2,
    const float* __restrict__ hw2, const float* __restrict__ hb2,
    float* __restrict__ hin)
{
    __shared__ float zs[2][48];
    __shared__ float h1[16][128];
    __shared__ float es[16][128];
    int tid = threadIdx.x;
    if (tid < 96) zs[tid/48][tid%48] = seidel[tid];
    __syncthreads();
    #pragma unroll 4
    for (int i = 0; i < 16; ++i) {
        int s = i >> 3, conv = (i >> 2) & 1, m = i & 3;
        const float* W1 = conv ? m2W1 : m1W1;
        const float* b1 = conv ? m2b1 : m1b1;
        float a = b1[m*128 + tid];
        for (int k = 0; k < 48; ++k) a += zs[s][k] * W1[(m*48 + k)*128 + tid];
        h1[i][tid] = fmaxf(a, 0.f);
    }
    __syncthreads();
    #pragma unroll 4
    for (int i = 0; i < 16; ++i) {
        int conv = (i >> 2) & 1, m = i & 3;
        const float* W2 = conv ? m2W2 : m1W2;
        const float* b2 = conv ? m2b2 : m1b2;
        float a = b2[m*128 + tid];
        for (int k = 0; k < 128; ++k) a += h1[i][k] * W2[(m*128 + k)*128 + tid];
        es[i][tid] = fmaxf(a, 0.f);
    }
    __syncthreads();
    int j = blockIdx.x*128 + tid;
    float acc[16];
    float b = hb2[j];
    #pragma unroll
    for (int c = 0; c < 16; ++c) acc[c] = b;
    for (int i = 0; i < 128; ++i) {
        float wv = hw2[(size_t)i*8192 + j];
        #pragma unroll
        for (int c = 0; c < 16; ++c) acc[c] += es[c][i]*wv;
    }
    #pragma unroll
    for (int c = 0; c < 16; ++c) hin[(size_t)c*8192 + j] = acc[c];
}

// ============================================================
// Kernel 2a: transpose hw1 [128 k][4608 j] -> hw1t [4608 j][128 k]
// ============================================================
__global__ void hw1t_kernel(const float* __restrict__ in, float* __restrict__ out)
{
    __shared__ float tile[32][33];
    int j0 = blockIdx.x*32, k0 = blockIdx.y*32;
    int tx = threadIdx.x, ty = threadIdx.y;
    #pragma unroll
    for (int i = 0; i < 4; ++i) tile[ty + i*8][tx] = in[(size_t)(k0 + ty + i*8)*4608 + j0 + tx];
    __syncthreads();
    #pragma unroll
    for (int i = 0; i < 4; ++i) out[(size_t)(j0 + ty + i*8)*128 + k0 + tx] = tile[tx][ty + i*8];
}

// ============================================================
// Kernel 2b: h_fin via MFMA (f16 inputs, f32 acc) + coalesced scatter.
// grid (72 = r*9+tap, 16 combos), 256 thr = 4 waves.
// wtab [sc][r 8][chunk 4][tap 9][co 128][ci32] f16
// ============================================================
__global__ __launch_bounds__(256) void hfin3_kernel(
    const float* __restrict__ hin, const float* __restrict__ hw1t,
    const float* __restrict__ hb1, f16* __restrict__ wtab)
{
    int c72 = blockIdx.x;
    int combo = blockIdx.y;
    int r = c72 / 9, tap = c72 - r*9;
    int s = combo >> 3, conv = (combo >> 2) & 1, m = combo & 3;
    __shared__ f16 A[64][136];
    __shared__ f16 B[64][136];
    __shared__ f16 ct[64][72];
    int tid = threadIdx.x;
    const float4* hsrc = (const float4*)(hin + (size_t)combo*8192);
    for (int i = tid; i < 2048; i += 256) {
        int a = i >> 5, k4 = (i & 31)*4;
        float4 v = hsrc[i];
        half4_t h; h[0]=(f16)v.x; h[1]=(f16)v.y; h[2]=(f16)v.z; h[3]=(f16)v.w;
        *(half4_t*)&A[a][k4] = h;
    }
    for (int i = tid; i < 2048; i += 256) {
        int b = i >> 5, k4 = (i & 31)*4;
        float4 v = *(const float4*)(hw1t + (size_t)(b*72 + c72)*128 + k4);
        half4_t h; h[0]=(f16)v.x; h[1]=(f16)v.y; h[2]=(f16)v.z; h[3]=(f16)v.w;
        *(half4_t*)&B[b][k4] = h;
    }
    __syncthreads();
    int lane = tid & 63, wid = tid >> 6;
    int wa = wid & 1, wb = wid >> 1;
    int l31 = lane & 31, lq = lane >> 5;
    floatx16 c = (floatx16)0.f;
    #pragma unroll
    for (int k = 0; k < 8; ++k) {
        half8 af = *(const half8*)&A[wa*32 + l31][k*16 + lq*8];
        half8 bf = *(const half8*)&B[wb*32 + l31][k*16 + lq*8];
        c = __builtin_amdgcn_mfma_f32_32x32x16_f16(af, bf, c, 0, 0, 0);
    }
    int bcol = wb*32 + l31;
    float bias = hb1[bcol*72 + c72];
    #pragma unroll
    for (int rr = 0; rr < 16; ++rr) {
        int a = wa*32 + (rr & 3) + 8*(rr >> 2) + 4*lq;
        ct[a][bcol] = (f16)(c[rr] + bias);
    }
    __syncthreads();
    {
        int a = tid & 63, q = tid >> 6;
        int chunk = (m & 1)*2 + (q >> 1);
        int co = (m >> 1)*64 + a;
        f16* dst = wtab + (((((size_t)(s*2 + conv)*8 + r)*4 + chunk)*9 + tap)*128 + co)*32
                   + (q & 1)*16;
        *(half8*)(dst)     = *(const half8*)&ct[a][q*16];
        *(half8*)(dst + 8) = *(const half8*)&ct[a][q*16 + 8];
    }
}

// ============================================================
// Kernel 3: x [s][c][h][w] f32 -> xt [s][w][h][c] f16. grid (256 h, 2 s)
// Also zeroes the 64 B zero-page (block 0,0).
// ============================================================
__global__ __launch_bounds__(256) void xpose_cast2(
    const float* __restrict__ in, f16* __restrict__ out, float4* __restrict__ zerop)
{
    __shared__ f16 tileT[128*136];
    int h = blockIdx.x, s = blockIdx.y;
    int tid = threadIdx.x;
    if (h == 0 && s == 0 && tid < 4) zerop[tid] = make_float4(0.f, 0.f, 0.f, 0.f);
    int cg = tid >> 5, q2 = tid & 31;
    const float* src = in + (size_t)s*4194304 + (size_t)h*128;
    for (int pass = 0; pass < 16; ++pass) {
        int c = pass*8 + cg;
        float4 v = *(const float4*)(src + (size_t)c*32768 + q2*4);
        tileT[(q2*4 + 0)*136 + c] = (f16)v.x;
        tileT[(q2*4 + 1)*136 + c] = (f16)v.y;
        tileT[(q2*4 + 2)*136 + c] = (f16)v.z;
        tileT[(q2*4 + 3)*136 + c] = (f16)v.w;
    }
    __syncthreads();
    int ww = tid >> 1, hf = tid & 1;
    const f16* srcT = &tileT[ww*136 + hf*64];
    f16* dst = out + (((size_t)(s*128 + ww)*256 + h)*128) + hf*64;
    #pragma unroll
    for (int i = 0; i < 8; ++i)
        *(float4*)(dst + i*8) = *(const float4*)(srcT + i*8);
}

// ============================================================
// Kernel 5: y2t [s*co][w][h] f32 -> out [s*co][h][w] f32
// ============================================================
__global__ void xpose_out(const float* __restrict__ in, float* __restrict__ out)
{
    __shared__ float tile[32][33];
    int sc = blockIdx.z;
    int w0 = blockIdx.x*32, h0 = blockIdx.y*32;
    int tx = threadIdx.x, ty = threadIdx.y;
    const float* src = in + ((size_t)sc*128 + w0)*256 + h0;
    #pragma unroll
    for (int i = 0; i < 4; ++i) tile[ty + i*8][tx] = src[(size_t)(ty + i*8)*256 + tx];
    __syncthreads();
    float* dst = out + ((size_t)sc*256 + h0)*128 + w0;
    #pragma unroll
    for (int i = 0; i < 4; ++i) dst[(size_t)(ty + i*8)*128 + tx] = tile[tx][ty + i*8];
}

// ============================================================
// Kernel 4: MFMA LRI conv + BN + ReLU, v14 = r12's conv_mfma11
// (best measured: 42.4 us) with s_setprio REMOVED (m190: setprio is
// null-to-negative on barrier-lockstep GEMM structures).
// xin [s][w 128][h 256][c 128] f16. grid 256: xcd=b&7 -> s=xcd>>2,
// w=(xcd&3)*32 + (b>>3). 512 thr = 8 waves; block = 128co x 256h.
// Wave (wc=wid&1, wh=wid>>1): 64co x 64h, 2x2 frags of 32x32.
// Per step hc (16 ci): loadw(next) FIRST (asm-pinned regs) + stage_x(next)
// 3 gll -> taps 0..3 -> write_w(next) -> taps 4..8 -> ONE barrier.
// smW dbuf 2x36864; smX dbuf 2x24576 (circular h, OOB -> zero page).
// ============================================================
template<int OUT_F16>
__global__ __launch_bounds__(512, 1) void conv_mfma14(
    const f16* __restrict__ xin,
    const f16* __restrict__ wtab,
    int conv,
    const float* __restrict__ bng, const float* __restrict__ bnb,
    void* __restrict__ outp,
    const float4* __restrict__ zerop)
{
    int b = blockIdx.x;
    int xcd = b & 7, i = b >> 3;
    int s = xcd >> 2;
    int w = (xcd & 3)*32 + i;
    const f16* xs  = xin  + (size_t)s*4194304;
    const f16* wts = wtab + (size_t)(s*2 + conv)*1179648;

    float fsrc = fminf(fmaxf((w + 0.5f)*0.0625f - 0.5f, 0.f), 7.f);
    int r0 = (int)fsrc, r1 = min(r0 + 1, 7);
    f16 th = (f16)(fsrc - (float)r0);

    __shared__ __align__(16) char sbuf[122880];  // smW 2x36864 | smX 2x24576

    int tid = threadIdx.x;
    int lane = tid & 63, wid = tid >> 6;
    int wc = wid & 1, wh = wid >> 1;             // wh 0..3
    int l31 = lane & 31, lq = lane >> 5;

    floatx16 acc[2][2];
    #pragma unroll
    for (int a = 0; a < 2; ++a)
        #pragma unroll
        for (int c = 0; c < 2; ++c) acc[a][c] = (floatx16)0.f;

    half8 wa[5], wb[5];

    // weight loads: issued FIRST each step (oldest in vmcnt), pinned in regs
    auto loadw = [&](int hc) {
        int chunk = hc >> 1, half = hc & 1;
        #pragma unroll
        for (int p = 0; p < 5; ++p) {
            int sl = p*512 + tid;
            if (sl < 2304) {
                int tap = sl >> 8, rem = sl & 255;
                int part = rem >> 7, co = rem & 127;
                size_t off = (size_t)co*32 + half*16 + part*8;
                wa[p] = *(const half8*)(wts + (((size_t)(r0*4 + chunk)*9 + tap) << 12) + off);
                wb[p] = *(const half8*)(wts + (((size_t)(r1*4 + chunk)*9 + tap) << 12) + off);
            }
            asm volatile("" : "+v"(wa[p]), "+v"(wb[p]));
        }
    };
    auto stage_x = [&](int bsel, int hc) {
        char* xb = sbuf + 73728 + bsel*24576;
        #pragma unroll
        for (int it = 0; it < 3; ++it) {
            int id = it*512 + tid;
            int dj = id >> 9, part = (id >> 8) & 1, hp = id & 255;
            int wsg = w + dj - 1;
            const void* src = (wsg >= 0 && wsg < 128)
                ? (const void*)(xs + ((size_t)wsg*256 + hp)*128 + hc*16 + part*8)
                : (const void*)zerop;
            gll16(src, xb + (size_t)(it*512 + wid*64)*16);
        }
    };
    auto write_w = [&](int bsel) {
        char* wbase = sbuf + bsel*36864;
        #pragma unroll
        for (int p = 0; p < 5; ++p) {
            int sl = p*512 + tid;
            if (sl < 2304) {
                half8 o = wa[p] + (wb[p] - wa[p])*th;
                *(half8*)(wbase + (size_t)sl*16) = o;
            }
        }
    };

    // ---- prologue: stage step 0 ----
    loadw(0);
    stage_x(0, 0);
    write_w(0);
    __syncthreads();

    #pragma unroll 2
    for (int hc = 0; hc < 8; ++hc) {
        int cur = hc & 1;
        if (hc < 7) { loadw(hc + 1); stage_x(cur ^ 1, hc + 1); }
        const char* wbuf = sbuf + cur*36864;
        const f16* xb = (const f16*)(sbuf + 73728 + cur*24576);

        #pragma unroll
        for (int tap = 0; tap < 4; ++tap) {
            int di = tap/3, dj = tap - di*3;
            half8 af0 = *(const half8*)(wbuf + (size_t)(tap*256 + lq*128 + wc*64 + l31)*16);
            half8 af1 = *(const half8*)(wbuf + (size_t)(tap*256 + lq*128 + wc*64 + 32 + l31)*16);
            int h0 = wh*64 + l31 + di - 1;
            half8 bf0 = *(const half8*)(xb + (size_t)(dj*512 + lq*256 + (h0 & 255))*8);
            half8 bf1 = *(const half8*)(xb + (size_t)(dj*512 + lq*256 + ((h0 + 32) & 255))*8);
            acc[0][0] = __builtin_amdgcn_mfma_f32_32x32x16_f16(af0, bf0, acc[0][0], 0, 0, 0);
            acc[0][1] = __builtin_amdgcn_mfma_f32_32x32x16_f16(af0, bf1, acc[0][1], 0, 0, 0);
            acc[1][0] = __builtin_amdgcn_mfma_f32_32x32x16_f16(af1, bf0, acc[1][0], 0, 0, 0);
            acc[1][1] = __builtin_amdgcn_mfma_f32_32x32x16_f16(af1, bf1, acc[1][1], 0, 0, 0);
        }
        if (hc < 7) write_w(cur ^ 1);   // one vmcnt wait (weights); glls keep flying
        #pragma unroll
        for (int tap = 4; tap < 9; ++tap) {
            int di = tap/3, dj = tap - di*3;
            half8 af0 = *(const half8*)(wbuf + (size_t)(tap*256 + lq*128 + wc*64 + l31)*16);
            half8 af1 = *(const half8*)(wbuf + (size_t)(tap*256 + lq*128 + wc*64 + 32 + l31)*16);
            int h0 = wh*64 + l31 + di - 1;
            half8 bf0 = *(const half8*)(xb + (size_t)(dj*512 + lq*256 + (h0 & 255))*8);
            half8 bf1 = *(const half8*)(xb + (size_t)(dj*512 + lq*256 + ((h0 + 32) & 255))*8);
            acc[0][0] = __builtin_amdgcn_mfma_f32_32x32x16_f16(af0, bf0, acc[0][0], 0, 0, 0);
            acc[0][1] = __builtin_amdgcn_mfma_f32_32x32x16_f16(af0, bf1, acc[0][1], 0, 0, 0);
            acc[1][0] = __builtin_amdgcn_mfma_f32_32x32x16_f16(af1, bf0, acc[1][0], 0, 0, 0);
            acc[1][1] = __builtin_amdgcn_mfma_f32_32x32x16_f16(af1, bf1, acc[1][1], 0, 0, 0);
        }
        __syncthreads();
    }

    // ---- epilogue: BN + ReLU, store ----
    float rs = rsqrtf(1.f + 1e-5f);
    if (OUT_F16) {
        f16* otile = (f16*)sbuf;           // [128][136], two h-phases
        f16* yout = (f16*)outp + ((size_t)(s*128 + w)*256)*128;
        #pragma unroll
        for (int ph = 0; ph < 2; ++ph) {
            __syncthreads();
            if ((wh >> 1) == ph) {
                #pragma unroll
                for (int ct = 0; ct < 2; ++ct) {
                    #pragma unroll
                    for (int ht = 0; ht < 2; ++ht) {
                        int hrow = (wh & 1)*64 + ht*32 + l31;
                        #pragma unroll
                        for (int rq = 0; rq < 4; ++rq) {
                            int cb = wc*64 + ct*32 + rq*8 + lq*4;
                            float4 g4 = *(const float4*)&bng[cb];
                            float4 b4 = *(const float4*)&bnb[cb];
                            half4_t v;
                            #pragma unroll
                            for (int e = 0; e < 4; ++e) {
                                float g = (&g4.x)[e], bb = (&b4.x)[e];
                                v[e] = (f16)fmaxf(acc[ct][ht][rq*4 + e]*g*rs + bb, 0.f);
                            }
                            *(half4_t*)&otile[hrow*136 + cb] = v;
                        }
                    }
                }
            }
            __syncthreads();
            {
                int hrow = tid >> 2, qc = tid & 3;
                const f16* srcT = &otile[hrow*136 + qc*32];
                f16* d = yout + (size_t)(ph*128 + hrow)*128 + qc*32;
                #pragma unroll
                for (int k = 0; k < 4; ++k)
                    *(float4*)(d + k*8) = *(const float4*)(srcT + k*8);
            }
        }
    } else {
        #pragma unroll
        for (int ct = 0; ct < 2; ++ct) {
            #pragma unroll
            for (int ht = 0; ht < 2; ++ht) {
                int hrow = wh*64 + ht*32 + l31;
                #pragma unroll
                for (int r = 0; r < 16; ++r) {
                    int co = wc*64 + ct*32 + (r & 3) + 8*(r >> 2) + 4*lq;
                    float v = fmaxf(acc[ct][ht][r]*bng[co]*rs + bnb[co], 0.f);
                    ((float*)outp)[((size_t)(s*128 + co)*128 + w)*256 + hrow] = v;
                }
            }
        }
    }
}

// ============================================================
extern "C" void kernel_launch(void* const* d_in, const int* in_sizes, int n_in,
                              void* d_out, int out_size, void* d_ws, size_t ws_size,
                              hipStream_t stream) {
    const float* x      = (const float*)d_in[0];
    const float* seidel = (const float*)d_in[1];
    const float* m1W1 = (const float*)d_in[2];
    const float* m1b1 = (const float*)d_in[3];
    const float* m1W2 = (const float*)d_in[4];
    const float* m1b2 = (const float*)d_in[5];
    const float* m2W1 = (const float*)d_in[6];
    const float* m2b1 = (const float*)d_in[7];
    const float* m2W2 = (const float*)d_in[8];
    const float* m2b2 = (const float*)d_in[9];
    const float* hw2  = (const float*)d_in[10];
    const float* hb2  = (const float*)d_in[11];
    const float* hw1  = (const float*)d_in[12];
    const float* hb1  = (const float*)d_in[13];
    const float* bn1g = (const float*)d_in[14];
    const float* bn1b = (const float*)d_in[15];
    const float* bn2g = (const float*)d_in[16];
    const float* bn2b = (const float*)d_in[17];
    float* outp = (float*)d_out;

    char* wsb = (char*)d_ws;
    // region map (lifetimes disjoint where overlapped):
    f16*   wtab = (f16*)wsb;                            // 0 .. 9437184
    f16*   y1t  = (f16*)(wsb + 9437184);                // 16777216
    f16*   xt   = (f16*)(wsb + 26214400);               // 16777216 (conv1 input)
    float* y2t  = (float*)(wsb + 26214400);             // 33554432 (overlays xt, born conv2)
    float4* zerop = (float4*)(wsb + 59768832);          // 64 B zero page
    // short-lived buffers inside xt region (dead before xpose_cast2 writes xt):
    float* hin  = (float*)(wsb + 26214400);             // 524288
    float* hw1t = (float*)(wsb + 26214400 + 1048576);   // 2359296

    embed_ab<<<64, 128, 0, stream>>>(seidel, m1W1, m1b1, m1W2, m1b2,
                                     m2W1, m2b1, m2W2, m2b2, hw2, hb2, hin);
    hw1t_kernel<<<dim3(144, 4), dim3(32, 8), 0, stream>>>(hw1, hw1t);
    hfin3_kernel<<<dim3(72, 16), 256, 0, stream>>>(hin, hw1t, hb1, wtab);
    xpose_cast2<<<dim3(256, 2), 256, 0, stream>>>(x, xt, zerop);
    conv_mfma14<1><<<256, 512, 0, stream>>>(xt, wtab, 0, bn1g, bn1b, (void*)y1t, zerop);
    conv_mfma14<0><<<256, 512, 0, stream>>>(y1t, wtab, 1, bn2g, bn2b, (void*)y2t, zerop);
    xpose_out<<<dim3(4, 8, 256), dim3(32, 8), 0, stream>>>(y2t, outp);
}

// Round 17
// 139.816 us; speedup vs baseline: 1.4507x; 1.4507x over previous
//
#include <hip/hip_runtime.h>
#include <hip/hip_bf16.h>

typedef _Float16 f16;
typedef _Float16 half8 __attribute__((ext_vector_type(8)));
typedef _Float16 half4_t __attribute__((ext_vector_type(4)));
typedef float floatx16 __attribute__((ext_vector_type(16)));

__device__ __forceinline__ void gll16(const void* g, void* l) {
    __builtin_amdgcn_global_load_lds(
        (const __attribute__((address_space(1))) void*)g,
        (__attribute__((address_space(3))) void*)l, 16, 0, 0);
}

// ============================================================
// Kernel 1a: per-(s,conv,m) MLP -> embedding e (128). grid 16, 256 thr.
// ============================================================
__global__ __launch_bounds__(256) void embed_a(
    const float* __restrict__ seidel,
    const float* __restrict__ m1W1, const float* __restrict__ m1b1,
    const float* __restrict__ m1W2, const float* __restrict__ m1b2,
    const float* __restrict__ m2W1, const float* __restrict__ m2b1,
    const float* __restrict__ m2W2, const float* __restrict__ m2b2,
    float* __restrict__ eout)
{
    int combo = blockIdx.x;                 // (s*2+conv)*4 + m
    int s = combo >> 3, conv = (combo >> 2) & 1, m = combo & 3;
    const float* W1 = conv ? m2W1 : m1W1;
    const float* b1 = conv ? m2b1 : m1b1;
    const float* W2 = conv ? m2W2 : m1W2;
    const float* b2 = conv ? m2b2 : m1b2;
    __shared__ float zs[48], hbuf[128];
    int tid = threadIdx.x;
    if (tid < 48) zs[tid] = seidel[s*48 + tid];
    __syncthreads();
    if (tid < 128) {
        float a = b1[m*128 + tid];
        for (int i = 0; i < 48; ++i) a += zs[i] * W1[(m*48 + i)*128 + tid];
        hbuf[tid] = fmaxf(a, 0.f);
    }
    __syncthreads();
    if (tid < 128) {
        float a = b2[m*128 + tid];
        for (int i = 0; i < 128; ++i) a += hbuf[i] * W2[(m*128 + i)*128 + tid];
        eout[combo*128 + tid] = fmaxf(a, 0.f);
    }
}

// ============================================================
// Kernel 1b: h_in = e @ hyp_w2 + hyp_b2.  grid 64, 128 thr.
// ============================================================
__global__ __launch_bounds__(128) void embed_b3(
    const float* __restrict__ eout, const float* __restrict__ hw2,
    const float* __restrict__ hb2, float* __restrict__ hin)
{
    __shared__ float es[16][128];
    int tid = threadIdx.x;
    int j = blockIdx.x*128 + tid;
    for (int i = tid; i < 2048; i += 128) es[i >> 7][i & 127] = eout[i];
    __syncthreads();
    float acc[16];
    float b = hb2[j];
    #pragma unroll
    for (int c = 0; c < 16; ++c) acc[c] = b;
    for (int i = 0; i < 128; ++i) {
        float wv = hw2[(size_t)i*8192 + j];
        #pragma unroll
        for (int c = 0; c < 16; ++c) acc[c] += es[c][i]*wv;
    }
    #pragma unroll
    for (int c = 0; c < 16; ++c) hin[(size_t)c*8192 + j] = acc[c];
}

// ============================================================
// Kernel 2a: transpose hw1 [128 k][4608 j] -> hw1t [4608 j][128 k]
// ============================================================
__global__ void hw1t_kernel(const float* __restrict__ in, float* __restrict__ out)
{
    __shared__ float tile[32][33];
    int j0 = blockIdx.x*32, k0 = blockIdx.y*32;
    int tx = threadIdx.x, ty = threadIdx.y;
    #pragma unroll
    for (int i = 0; i < 4; ++i) tile[ty + i*8][tx] = in[(size_t)(k0 + ty + i*8)*4608 + j0 + tx];
    __syncthreads();
    #pragma unroll
    for (int i = 0; i < 4; ++i) out[(size_t)(j0 + ty + i*8)*128 + k0 + tx] = tile[tx][ty + i*8];
}

// ============================================================
// Kernel 2b: h_fin via MFMA (f16 inputs, f32 acc) + coalesced scatter.
// grid (72 = r*9+tap, 16 combos), 256 thr = 4 waves.
// wtab [sc][r 8][chunk 4][tap 9][co 128][ci32] f16
// ============================================================
__global__ __launch_bounds__(256) void hfin3_kernel(
    const float* __restrict__ hin, const float* __restrict__ hw1t,
    const float* __restrict__ hb1, f16* __restrict__ wtab)
{
    int c72 = blockIdx.x;
    int combo = blockIdx.y;
    int r = c72 / 9, tap = c72 - r*9;
    int s = combo >> 3, conv = (combo >> 2) & 1, m = combo & 3;
    __shared__ f16 A[64][136];
    __shared__ f16 B[64][136];
    __shared__ f16 ct[64][72];
    int tid = threadIdx.x;
    const float4* hsrc = (const float4*)(hin + (size_t)combo*8192);
    for (int i = tid; i < 2048; i += 256) {
        int a = i >> 5, k4 = (i & 31)*4;
        float4 v = hsrc[i];
        half4_t h; h[0]=(f16)v.x; h[1]=(f16)v.y; h[2]=(f16)v.z; h[3]=(f16)v.w;
        *(half4_t*)&A[a][k4] = h;
    }
    for (int i = tid; i < 2048; i += 256) {
        int b = i >> 5, k4 = (i & 31)*4;
        float4 v = *(const float4*)(hw1t + (size_t)(b*72 + c72)*128 + k4);
        half4_t h; h[0]=(f16)v.x; h[1]=(f16)v.y; h[2]=(f16)v.z; h[3]=(f16)v.w;
        *(half4_t*)&B[b][k4] = h;
    }
    __syncthreads();
    int lane = tid & 63, wid = tid >> 6;
    int wa = wid & 1, wb = wid >> 1;
    int l31 = lane & 31, lq = lane >> 5;
    floatx16 c = (floatx16)0.f;
    #pragma unroll
    for (int k = 0; k < 8; ++k) {
        half8 af = *(const half8*)&A[wa*32 + l31][k*16 + lq*8];
        half8 bf = *(const half8*)&B[wb*32 + l31][k*16 + lq*8];
        c = __builtin_amdgcn_mfma_f32_32x32x16_f16(af, bf, c, 0, 0, 0);
    }
    int bcol = wb*32 + l31;
    float bias = hb1[bcol*72 + c72];
    #pragma unroll
    for (int rr = 0; rr < 16; ++rr) {
        int a = wa*32 + (rr & 3) + 8*(rr >> 2) + 4*lq;
        ct[a][bcol] = (f16)(c[rr] + bias);
    }
    __syncthreads();
    {
        int a = tid & 63, q = tid >> 6;
        int chunk = (m & 1)*2 + (q >> 1);
        int co = (m >> 1)*64 + a;
        f16* dst = wtab + (((((size_t)(s*2 + conv)*8 + r)*4 + chunk)*9 + tap)*128 + co)*32
                   + (q & 1)*16;
        *(half8*)(dst)     = *(const half8*)&ct[a][q*16];
        *(half8*)(dst + 8) = *(const half8*)&ct[a][q*16 + 8];
    }
}

// ============================================================
// Kernel 3: x [s][c][h][w] f32 -> xt [s][w][h][c] f16. grid (256 h, 2 s)
// Also zeroes the 64 B zero-page (block 0,0).
// ============================================================
__global__ __launch_bounds__(256) void xpose_cast2(
    const float* __restrict__ in, f16* __restrict__ out, float4* __restrict__ zerop)
{
    __shared__ f16 tileT[128*136];
    int h = blockIdx.x, s = blockIdx.y;
    int tid = threadIdx.x;
    if (h == 0 && s == 0 && tid < 4) zerop[tid] = make_float4(0.f, 0.f, 0.f, 0.f);
    int cg = tid >> 5, q2 = tid & 31;
    const float* src = in + (size_t)s*4194304 + (size_t)h*128;
    for (int pass = 0; pass < 16; ++pass) {
        int c = pass*8 + cg;
        float4 v = *(const float4*)(src + (size_t)c*32768 + q2*4);
        tileT[(q2*4 + 0)*136 + c] = (f16)v.x;
        tileT[(q2*4 + 1)*136 + c] = (f16)v.y;
        tileT[(q2*4 + 2)*136 + c] = (f16)v.z;
        tileT[(q2*4 + 3)*136 + c] = (f16)v.w;
    }
    __syncthreads();
    int ww = tid >> 1, hf = tid & 1;
    const f16* srcT = &tileT[ww*136 + hf*64];
    f16* dst = out + (((size_t)(s*128 + ww)*256 + h)*128) + hf*64;
    #pragma unroll
    for (int i = 0; i < 8; ++i)
        *(float4*)(dst + i*8) = *(const float4*)(srcT + i*8);
}

// ============================================================
// Kernel 5: y2t [s*co][w][h] f32 -> out [s*co][h][w] f32
// ============================================================
__global__ void xpose_out(const float* __restrict__ in, float* __restrict__ out)
{
    __shared__ float tile[32][33];
    int sc = blockIdx.z;
    int w0 = blockIdx.x*32, h0 = blockIdx.y*32;
    int tx = threadIdx.x, ty = threadIdx.y;
    const float* src = in + ((size_t)sc*128 + w0)*256 + h0;
    #pragma unroll
    for (int i = 0; i < 4; ++i) tile[ty + i*8][tx] = src[(size_t)(ty + i*8)*256 + tx];
    __syncthreads();
    float* dst = out + ((size_t)sc*256 + h0)*128 + w0;
    #pragma unroll
    for (int i = 0; i < 4; ++i) dst[(size_t)(ty + i*8)*128 + tx] = tile[tx][ty + i*8];
}

// ============================================================
// Kernel 4: MFMA LRI conv + BN + ReLU, v14 = r12's conv_mfma11
// with s_setprio removed (clean A/B vs r12's 42.4 us this round).
// xin [s][w 128][h 256][c 128] f16. grid 256: xcd=b&7 -> s=xcd>>2,
// w=(xcd&3)*32 + (b>>3). 512 thr = 8 waves; block = 128co x 256h.
// Wave (wc=wid&1, wh=wid>>1): 64co x 64h, 2x2 frags of 32x32.
// Per step hc (16 ci): loadw(next) FIRST (asm-pinned regs) + stage_x(next)
// 3 gll -> taps 0..3 -> write_w(next) -> taps 4..8 -> ONE barrier.
// smW dbuf 2x36864; smX dbuf 2x24576 (circular h, OOB -> zero page).
// ============================================================
template<int OUT_F16>
__global__ __launch_bounds__(512, 1) void conv_mfma14(
    const f16* __restrict__ xin,
    const f16* __restrict__ wtab,
    int conv,
    const float* __restrict__ bng, const float* __restrict__ bnb,
    void* __restrict__ outp,
    const float4* __restrict__ zerop)
{
    int b = blockIdx.x;
    int xcd = b & 7, i = b >> 3;
    int s = xcd >> 2;
    int w = (xcd & 3)*32 + i;
    const f16* xs  = xin  + (size_t)s*4194304;
    const f16* wts = wtab + (size_t)(s*2 + conv)*1179648;

    float fsrc = fminf(fmaxf((w + 0.5f)*0.0625f - 0.5f, 0.f), 7.f);
    int r0 = (int)fsrc, r1 = min(r0 + 1, 7);
    f16 th = (f16)(fsrc - (float)r0);

    __shared__ __align__(16) char sbuf[122880];  // smW 2x36864 | smX 2x24576

    int tid = threadIdx.x;
    int lane = tid & 63, wid = tid >> 6;
    int wc = wid & 1, wh = wid >> 1;             // wh 0..3
    int l31 = lane & 31, lq = lane >> 5;

    floatx16 acc[2][2];
    #pragma unroll
    for (int a = 0; a < 2; ++a)
        #pragma unroll
        for (int c = 0; c < 2; ++c) acc[a][c] = (floatx16)0.f;

    half8 wa[5], wb[5];

    // weight loads: issued FIRST each step (oldest in vmcnt), pinned in regs
    auto loadw = [&](int hc) {
        int chunk = hc >> 1, half = hc & 1;
        #pragma unroll
        for (int p = 0; p < 5; ++p) {
            int sl = p*512 + tid;
            if (sl < 2304) {
                int tap = sl >> 8, rem = sl & 255;
                int part = rem >> 7, co = rem & 127;
                size_t off = (size_t)co*32 + half*16 + part*8;
                wa[p] = *(const half8*)(wts + (((size_t)(r0*4 + chunk)*9 + tap) << 12) + off);
                wb[p] = *(const half8*)(wts + (((size_t)(r1*4 + chunk)*9 + tap) << 12) + off);
            }
            asm volatile("" : "+v"(wa[p]), "+v"(wb[p]));
        }
    };
    auto stage_x = [&](int bsel, int hc) {
        char* xb = sbuf + 73728 + bsel*24576;
        #pragma unroll
        for (int it = 0; it < 3; ++it) {
            int id = it*512 + tid;
            int dj = id >> 9, part = (id >> 8) & 1, hp = id & 255;
            int wsg = w + dj - 1;
            const void* src = (wsg >= 0 && wsg < 128)
                ? (const void*)(xs + ((size_t)wsg*256 + hp)*128 + hc*16 + part*8)
                : (const void*)zerop;
            gll16(src, xb + (size_t)(it*512 + wid*64)*16);
        }
    };
    auto write_w = [&](int bsel) {
        char* wbase = sbuf + bsel*36864;
        #pragma unroll
        for (int p = 0; p < 5; ++p) {
            int sl = p*512 + tid;
            if (sl < 2304) {
                half8 o = wa[p] + (wb[p] - wa[p])*th;
                *(half8*)(wbase + (size_t)sl*16) = o;
            }
        }
    };

    // ---- prologue: stage step 0 ----
    loadw(0);
    stage_x(0, 0);
    write_w(0);
    __syncthreads();

    #pragma unroll 2
    for (int hc = 0; hc < 8; ++hc) {
        int cur = hc & 1;
        if (hc < 7) { loadw(hc + 1); stage_x(cur ^ 1, hc + 1); }
        const char* wbuf = sbuf + cur*36864;
        const f16* xb = (const f16*)(sbuf + 73728 + cur*24576);

        #pragma unroll
        for (int tap = 0; tap < 4; ++tap) {
            int di = tap/3, dj = tap - di*3;
            half8 af0 = *(const half8*)(wbuf + (size_t)(tap*256 + lq*128 + wc*64 + l31)*16);
            half8 af1 = *(const half8*)(wbuf + (size_t)(tap*256 + lq*128 + wc*64 + 32 + l31)*16);
            int h0 = wh*64 + l31 + di - 1;
            half8 bf0 = *(const half8*)(xb + (size_t)(dj*512 + lq*256 + (h0 & 255))*8);
            half8 bf1 = *(const half8*)(xb + (size_t)(dj*512 + lq*256 + ((h0 + 32) & 255))*8);
            acc[0][0] = __builtin_amdgcn_mfma_f32_32x32x16_f16(af0, bf0, acc[0][0], 0, 0, 0);
            acc[0][1] = __builtin_amdgcn_mfma_f32_32x32x16_f16(af0, bf1, acc[0][1], 0, 0, 0);
            acc[1][0] = __builtin_amdgcn_mfma_f32_32x32x16_f16(af1, bf0, acc[1][0], 0, 0, 0);
            acc[1][1] = __builtin_amdgcn_mfma_f32_32x32x16_f16(af1, bf1, acc[1][1], 0, 0, 0);
        }
        if (hc < 7) write_w(cur ^ 1);   // one vmcnt wait (weights); glls keep flying
        #pragma unroll
        for (int tap = 4; tap < 9; ++tap) {
            int di = tap/3, dj = tap - di*3;
            half8 af0 = *(const half8*)(wbuf + (size_t)(tap*256 + lq*128 + wc*64 + l31)*16);
            half8 af1 = *(const half8*)(wbuf + (size_t)(tap*256 + lq*128 + wc*64 + 32 + l31)*16);
            int h0 = wh*64 + l31 + di - 1;
            half8 bf0 = *(const half8*)(xb + (size_t)(dj*512 + lq*256 + (h0 & 255))*8);
            half8 bf1 = *(const half8*)(xb + (size_t)(dj*512 + lq*256 + ((h0 + 32) & 255))*8);
            acc[0][0] = __builtin_amdgcn_mfma_f32_32x32x16_f16(af0, bf0, acc[0][0], 0, 0, 0);
            acc[0][1] = __builtin_amdgcn_mfma_f32_32x32x16_f16(af0, bf1, acc[0][1], 0, 0, 0);
            acc[1][0] = __builtin_amdgcn_mfma_f32_32x32x16_f16(af1, bf0, acc[1][0], 0, 0, 0);
            acc[1][1] = __builtin_amdgcn_mfma_f32_32x32x16_f16(af1, bf1, acc[1][1], 0, 0, 0);
        }
        __syncthreads();
    }

    // ---- epilogue: BN + ReLU, store ----
    float rs = rsqrtf(1.f + 1e-5f);
    if (OUT_F16) {
        f16* otile = (f16*)sbuf;           // [128][136], two h-phases
        f16* yout = (f16*)outp + ((size_t)(s*128 + w)*256)*128;
        #pragma unroll
        for (int ph = 0; ph < 2; ++ph) {
            __syncthreads();
            if ((wh >> 1) == ph) {
                #pragma unroll
                for (int ct = 0; ct < 2; ++ct) {
                    #pragma unroll
                    for (int ht = 0; ht < 2; ++ht) {
                        int hrow = (wh & 1)*64 + ht*32 + l31;
                        #pragma unroll
                        for (int rq = 0; rq < 4; ++rq) {
                            int cb = wc*64 + ct*32 + rq*8 + lq*4;
                            float4 g4 = *(const float4*)&bng[cb];
                            float4 b4 = *(const float4*)&bnb[cb];
                            half4_t v;
                            #pragma unroll
                            for (int e = 0; e < 4; ++e) {
                                float g = (&g4.x)[e], bb = (&b4.x)[e];
                                v[e] = (f16)fmaxf(acc[ct][ht][rq*4 + e]*g*rs + bb, 0.f);
                            }
                            *(half4_t*)&otile[hrow*136 + cb] = v;
                        }
                    }
                }
            }
            __syncthreads();
            {
                int hrow = tid >> 2, qc = tid & 3;
                const f16* srcT = &otile[hrow*136 + qc*32];
                f16* d = yout + (size_t)(ph*128 + hrow)*128 + qc*32;
                #pragma unroll
                for (int k = 0; k < 4; ++k)
                    *(float4*)(d + k*8) = *(const float4*)(srcT + k*8);
            }
        }
    } else {
        #pragma unroll
        for (int ct = 0; ct < 2; ++ct) {
            #pragma unroll
            for (int ht = 0; ht < 2; ++ht) {
                int hrow = wh*64 + ht*32 + l31;
                #pragma unroll
                for (int r = 0; r < 16; ++r) {
                    int co = wc*64 + ct*32 + (r & 3) + 8*(r >> 2) + 4*lq;
                    float v = fmaxf(acc[ct][ht][r]*bng[co]*rs + bnb[co], 0.f);
                    ((float*)outp)[((size_t)(s*128 + co)*128 + w)*256 + hrow] = v;
                }
            }
        }
    }
}

// ============================================================
extern "C" void kernel_launch(void* const* d_in, const int* in_sizes, int n_in,
                              void* d_out, int out_size, void* d_ws, size_t ws_size,
                              hipStream_t stream) {
    const float* x      = (const float*)d_in[0];
    const float* seidel = (const float*)d_in[1];
    const float* m1W1 = (const float*)d_in[2];
    const float* m1b1 = (const float*)d_in[3];
    const float* m1W2 = (const float*)d_in[4];
    const float* m1b2 = (const float*)d_in[5];
    const float* m2W1 = (const float*)d_in[6];
    const float* m2b1 = (const float*)d_in[7];
    const float* m2W2 = (const float*)d_in[8];
    const float* m2b2 = (const float*)d_in[9];
    const float* hw2  = (const float*)d_in[10];
    const float* hb2  = (const float*)d_in[11];
    const float* hw1  = (const float*)d_in[12];
    const float* hb1  = (const float*)d_in[13];
    const float* bn1g = (const float*)d_in[14];
    const float* bn1b = (const float*)d_in[15];
    const float* bn2g = (const float*)d_in[16];
    const float* bn2b = (const float*)d_in[17];
    float* outp = (float*)d_out;

    char* wsb = (char*)d_ws;
    // region map (lifetimes disjoint where overlapped):
    f16*   wtab = (f16*)wsb;                            // 0 .. 9437184
    f16*   y1t  = (f16*)(wsb + 9437184);                // 16777216
    f16*   xt   = (f16*)(wsb + 26214400);               // 16777216 (conv1 input)
    float* y2t  = (float*)(wsb + 26214400);             // 33554432 (overlays xt, born conv2)
    float4* zerop = (float4*)(wsb + 59768832);          // 64 B zero page
    // short-lived buffers inside xt region (dead before xpose_cast2 writes xt):
    float* hin  = (float*)(wsb + 26214400);             // 524288
    float* eout = (float*)(wsb + 26214400 + 524288);    // 8192
    float* hw1t = (float*)(wsb + 26214400 + 1048576);   // 2359296

    embed_a<<<16, 256, 0, stream>>>(seidel, m1W1, m1b1, m1W2, m1b2,
                                    m2W1, m2b1, m2W2, m2b2, eout);
    embed_b3<<<64, 128, 0, stream>>>(eout, hw2, hb2, hin);
    hw1t_kernel<<<dim3(144, 4), dim3(32, 8), 0, stream>>>(hw1, hw1t);
    hfin3_kernel<<<dim3(72, 16), 256, 0, stream>>>(hin, hw1t, hb1, wtab);
    xpose_cast2<<<dim3(256, 2), 256, 0, stream>>>(x, xt, zerop);
    conv_mfma14<1><<<256, 512, 0, stream>>>(xt, wtab, 0, bn1g, bn1b, (void*)y1t, zerop);
    conv_mfma14<0><<<256, 512, 0, stream>>>(y1t, wtab, 1, bn2g, bn2b, (void*)y2t, zerop);
    xpose_out<<<dim3(4, 8, 256), dim3(32, 8), 0, stream>>>(y2t, outp);
}

// Round 18
// 133.702 us; speedup vs baseline: 1.5170x; 1.0457x over previous
//
#include <hip/hip_runtime.h>
#include <hip/hip_bf16.h>

typedef _Float16 f16;
typedef _Float16 half8 __attribute__((ext_vector_type(8)));
typedef _Float16 half4_t __attribute__((ext_vector_type(4)));
typedef float floatx16 __attribute__((ext_vector_type(16)));

__device__ __forceinline__ void gll16(const void* g, void* l) {
    __builtin_amdgcn_global_load_lds(
        (const __attribute__((address_space(1))) void*)g,
        (__attribute__((address_space(3))) void*)l, 16, 0, 0);
}

// ============================================================
// Kernel P: fused independent prep (1104 blocks, 256 thr):
//   blocks [0,512):    x [s][c][h][w] f32 -> xt [s][w][h][c] f16  (+zerop)
//   blocks [512,528):  per-(s,conv,m) MLP -> embedding e (128)
//   blocks [528,1104): transpose hw1 -> hw1t
// ============================================================
__global__ __launch_bounds__(256) void prep_kernel(
    const float* __restrict__ x, f16* __restrict__ xt, float4* __restrict__ zerop,
    const float* __restrict__ seidel,
    const float* __restrict__ m1W1, const float* __restrict__ m1b1,
    const float* __restrict__ m1W2, const float* __restrict__ m1b2,
    const float* __restrict__ m2W1, const float* __restrict__ m2b1,
    const float* __restrict__ m2W2, const float* __restrict__ m2b2,
    float* __restrict__ eout,
    const float* __restrict__ hw1, float* __restrict__ hw1t)
{
    int b = blockIdx.x;
    int tid = threadIdx.x;
    if (b < 512) {
        // ---- xpose_cast2 ----
        __shared__ f16 tileT[128*136];
        int h = b & 255, s = b >> 8;
        if (b == 0 && tid < 4) zerop[tid] = make_float4(0.f, 0.f, 0.f, 0.f);
        int cg = tid >> 5, q2 = tid & 31;
        const float* src = x + (size_t)s*4194304 + (size_t)h*128;
        for (int pass = 0; pass < 16; ++pass) {
            int c = pass*8 + cg;
            float4 v = *(const float4*)(src + (size_t)c*32768 + q2*4);
            tileT[(q2*4 + 0)*136 + c] = (f16)v.x;
            tileT[(q2*4 + 1)*136 + c] = (f16)v.y;
            tileT[(q2*4 + 2)*136 + c] = (f16)v.z;
            tileT[(q2*4 + 3)*136 + c] = (f16)v.w;
        }
        __syncthreads();
        int ww = tid >> 1, hf = tid & 1;
        const f16* srcT = &tileT[ww*136 + hf*64];
        f16* dst = xt + (((size_t)(s*128 + ww)*256 + h)*128) + hf*64;
        #pragma unroll
        for (int i = 0; i < 8; ++i)
            *(float4*)(dst + i*8) = *(const float4*)(srcT + i*8);
    } else if (b < 528) {
        // ---- embed_a ----
        int combo = b - 512;                 // (s*2+conv)*4 + m
        int s = combo >> 3, conv = (combo >> 2) & 1, m = combo & 3;
        const float* W1 = conv ? m2W1 : m1W1;
        const float* b1 = conv ? m2b1 : m1b1;
        const float* W2 = conv ? m2W2 : m1W2;
        const float* b2 = conv ? m2b2 : m1b2;
        __shared__ float zs[48], hbuf[128];
        if (tid < 48) zs[tid] = seidel[s*48 + tid];
        __syncthreads();
        if (tid < 128) {
            float a = b1[m*128 + tid];
            for (int i = 0; i < 48; ++i) a += zs[i] * W1[(m*48 + i)*128 + tid];
            hbuf[tid] = fmaxf(a, 0.f);
        }
        __syncthreads();
        if (tid < 128) {
            float a = b2[m*128 + tid];
            for (int i = 0; i < 128; ++i) a += hbuf[i] * W2[(m*128 + i)*128 + tid];
            eout[combo*128 + tid] = fmaxf(a, 0.f);
        }
    } else {
        // ---- hw1t transpose ----
        __shared__ float tile[32][33];
        int idx = b - 528;
        int j0 = (idx % 144)*32, k0 = (idx / 144)*32;
        int tx = tid & 31, ty = tid >> 5;
        #pragma unroll
        for (int i = 0; i < 4; ++i)
            tile[ty + i*8][tx] = hw1[(size_t)(k0 + ty + i*8)*4608 + j0 + tx];
        __syncthreads();
        #pragma unroll
        for (int i = 0; i < 4; ++i)
            hw1t[(size_t)(j0 + ty + i*8)*128 + k0 + tx] = tile[tx][ty + i*8];
    }
}

// ============================================================
// Kernel 1b: h_in = e @ hyp_w2 + hyp_b2.  grid 64, 128 thr.
// ============================================================
__global__ __launch_bounds__(128) void embed_b3(
    const float* __restrict__ eout, const float* __restrict__ hw2,
    const float* __restrict__ hb2, float* __restrict__ hin)
{
    __shared__ float es[16][128];
    int tid = threadIdx.x;
    int j = blockIdx.x*128 + tid;
    for (int i = tid; i < 2048; i += 128) es[i >> 7][i & 127] = eout[i];
    __syncthreads();
    float acc[16];
    float b = hb2[j];
    #pragma unroll
    for (int c = 0; c < 16; ++c) acc[c] = b;
    for (int i = 0; i < 128; ++i) {
        float wv = hw2[(size_t)i*8192 + j];
        #pragma unroll
        for (int c = 0; c < 16; ++c) acc[c] += es[c][i]*wv;
    }
    #pragma unroll
    for (int c = 0; c < 16; ++c) hin[(size_t)c*8192 + j] = acc[c];
}

// ============================================================
// Kernel 2b: h_fin via MFMA (f16 inputs, f32 acc) + coalesced scatter.
// grid (72 = r*9+tap, 16 combos), 256 thr = 4 waves.
// wtab [sc][r 8][chunk 4][tap 9][co 128][ci32] f16
// ============================================================
__global__ __launch_bounds__(256) void hfin3_kernel(
    const float* __restrict__ hin, const float* __restrict__ hw1t,
    const float* __restrict__ hb1, f16* __restrict__ wtab)
{
    int c72 = blockIdx.x;
    int combo = blockIdx.y;
    int r = c72 / 9, tap = c72 - r*9;
    int s = combo >> 3, conv = (combo >> 2) & 1, m = combo & 3;
    __shared__ f16 A[64][136];
    __shared__ f16 B[64][136];
    __shared__ f16 ct[64][72];
    int tid = threadIdx.x;
    const float4* hsrc = (const float4*)(hin + (size_t)combo*8192);
    for (int i = tid; i < 2048; i += 256) {
        int a = i >> 5, k4 = (i & 31)*4;
        float4 v = hsrc[i];
        half4_t h; h[0]=(f16)v.x; h[1]=(f16)v.y; h[2]=(f16)v.z; h[3]=(f16)v.w;
        *(half4_t*)&A[a][k4] = h;
    }
    for (int i = tid; i < 2048; i += 256) {
        int b = i >> 5, k4 = (i & 31)*4;
        float4 v = *(const float4*)(hw1t + (size_t)(b*72 + c72)*128 + k4);
        half4_t h; h[0]=(f16)v.x; h[1]=(f16)v.y; h[2]=(f16)v.z; h[3]=(f16)v.w;
        *(half4_t*)&B[b][k4] = h;
    }
    __syncthreads();
    int lane = tid & 63, wid = tid >> 6;
    int wa = wid & 1, wb = wid >> 1;
    int l31 = lane & 31, lq = lane >> 5;
    floatx16 c = (floatx16)0.f;
    #pragma unroll
    for (int k = 0; k < 8; ++k) {
        half8 af = *(const half8*)&A[wa*32 + l31][k*16 + lq*8];
        half8 bf = *(const half8*)&B[wb*32 + l31][k*16 + lq*8];
        c = __builtin_amdgcn_mfma_f32_32x32x16_f16(af, bf, c, 0, 0, 0);
    }
    int bcol = wb*32 + l31;
    float bias = hb1[bcol*72 + c72];
    #pragma unroll
    for (int rr = 0; rr < 16; ++rr) {
        int a = wa*32 + (rr & 3) + 8*(rr >> 2) + 4*lq;
        ct[a][bcol] = (f16)(c[rr] + bias);
    }
    __syncthreads();
    {
        int a = tid & 63, q = tid >> 6;
        int chunk = (m & 1)*2 + (q >> 1);
        int co = (m >> 1)*64 + a;
        f16* dst = wtab + (((((size_t)(s*2 + conv)*8 + r)*4 + chunk)*9 + tap)*128 + co)*32
                   + (q & 1)*16;
        *(half8*)(dst)     = *(const half8*)&ct[a][q*16];
        *(half8*)(dst + 8) = *(const half8*)&ct[a][q*16 + 8];
    }
}

// ============================================================
// Kernel 5: y2t [s*co][w][h] f32 -> out [s*co][h][w] f32
// ============================================================
__global__ void xpose_out(const float* __restrict__ in, float* __restrict__ out)
{
    __shared__ float tile[32][33];
    int sc = blockIdx.z;
    int w0 = blockIdx.x*32, h0 = blockIdx.y*32;
    int tx = threadIdx.x, ty = threadIdx.y;
    const float* src = in + ((size_t)sc*128 + w0)*256 + h0;
    #pragma unroll
    for (int i = 0; i < 4; ++i) tile[ty + i*8][tx] = src[(size_t)(ty + i*8)*256 + tx];
    __syncthreads();
    float* dst = out + ((size_t)sc*256 + h0)*128 + w0;
    #pragma unroll
    for (int i = 0; i < 4; ++i) dst[(size_t)(ty + i*8)*128 + tx] = tile[tx][ty + i*8];
}

// ============================================================
// Kernel 4: MFMA LRI conv + BN + ReLU, v14 (unchanged from r17, best=42.0us).
// ============================================================
template<int OUT_F16>
__global__ __launch_bounds__(512, 1) void conv_mfma14(
    const f16* __restrict__ xin,
    const f16* __restrict__ wtab,
    int conv,
    const float* __restrict__ bng, const float* __restrict__ bnb,
    void* __restrict__ outp,
    const float4* __restrict__ zerop)
{
    int b = blockIdx.x;
    int xcd = b & 7, i = b >> 3;
    int s = xcd >> 2;
    int w = (xcd & 3)*32 + i;
    const f16* xs  = xin  + (size_t)s*4194304;
    const f16* wts = wtab + (size_t)(s*2 + conv)*1179648;

    float fsrc = fminf(fmaxf((w + 0.5f)*0.0625f - 0.5f, 0.f), 7.f);
    int r0 = (int)fsrc, r1 = min(r0 + 1, 7);
    f16 th = (f16)(fsrc - (float)r0);

    __shared__ __align__(16) char sbuf[122880];  // smW 2x36864 | smX 2x24576

    int tid = threadIdx.x;
    int lane = tid & 63, wid = tid >> 6;
    int wc = wid & 1, wh = wid >> 1;             // wh 0..3
    int l31 = lane & 31, lq = lane >> 5;

    floatx16 acc[2][2];
    #pragma unroll
    for (int a = 0; a < 2; ++a)
        #pragma unroll
        for (int c = 0; c < 2; ++c) acc[a][c] = (floatx16)0.f;

    half8 wa[5], wb[5];

    auto loadw = [&](int hc) {
        int chunk = hc >> 1, half = hc & 1;
        #pragma unroll
        for (int p = 0; p < 5; ++p) {
            int sl = p*512 + tid;
            if (sl < 2304) {
                int tap = sl >> 8, rem = sl & 255;
                int part = rem >> 7, co = rem & 127;
                size_t off = (size_t)co*32 + half*16 + part*8;
                wa[p] = *(const half8*)(wts + (((size_t)(r0*4 + chunk)*9 + tap) << 12) + off);
                wb[p] = *(const half8*)(wts + (((size_t)(r1*4 + chunk)*9 + tap) << 12) + off);
            }
            asm volatile("" : "+v"(wa[p]), "+v"(wb[p]));
        }
    };
    auto stage_x = [&](int bsel, int hc) {
        char* xb = sbuf + 73728 + bsel*24576;
        #pragma unroll
        for (int it = 0; it < 3; ++it) {
            int id = it*512 + tid;
            int dj = id >> 9, part = (id >> 8) & 1, hp = id & 255;
            int wsg = w + dj - 1;
            const void* src = (wsg >= 0 && wsg < 128)
                ? (const void*)(xs + ((size_t)wsg*256 + hp)*128 + hc*16 + part*8)
                : (const void*)zerop;
            gll16(src, xb + (size_t)(it*512 + wid*64)*16);
        }
    };
    auto write_w = [&](int bsel) {
        char* wbase = sbuf + bsel*36864;
        #pragma unroll
        for (int p = 0; p < 5; ++p) {
            int sl = p*512 + tid;
            if (sl < 2304) {
                half8 o = wa[p] + (wb[p] - wa[p])*th;
                *(half8*)(wbase + (size_t)sl*16) = o;
            }
        }
    };

    loadw(0);
    stage_x(0, 0);
    write_w(0);
    __syncthreads();

    #pragma unroll 2
    for (int hc = 0; hc < 8; ++hc) {
        int cur = hc & 1;
        if (hc < 7) { loadw(hc + 1); stage_x(cur ^ 1, hc + 1); }
        const char* wbuf = sbuf + cur*36864;
        const f16* xb = (const f16*)(sbuf + 73728 + cur*24576);

        #pragma unroll
        for (int tap = 0; tap < 4; ++tap) {
            int di = tap/3, dj = tap - di*3;
            half8 af0 = *(const half8*)(wbuf + (size_t)(tap*256 + lq*128 + wc*64 + l31)*16);
            half8 af1 = *(const half8*)(wbuf + (size_t)(tap*256 + lq*128 + wc*64 + 32 + l31)*16);
            int h0 = wh*64 + l31 + di - 1;
            half8 bf0 = *(const half8*)(xb + (size_t)(dj*512 + lq*256 + (h0 & 255))*8);
            half8 bf1 = *(const half8*)(xb + (size_t)(dj*512 + lq*256 + ((h0 + 32) & 255))*8);
            acc[0][0] = __builtin_amdgcn_mfma_f32_32x32x16_f16(af0, bf0, acc[0][0], 0, 0, 0);
            acc[0][1] = __builtin_amdgcn_mfma_f32_32x32x16_f16(af0, bf1, acc[0][1], 0, 0, 0);
            acc[1][0] = __builtin_amdgcn_mfma_f32_32x32x16_f16(af1, bf0, acc[1][0], 0, 0, 0);
            acc[1][1] = __builtin_amdgcn_mfma_f32_32x32x16_f16(af1, bf1, acc[1][1], 0, 0, 0);
        }
        if (hc < 7) write_w(cur ^ 1);
        #pragma unroll
        for (int tap = 4; tap < 9; ++tap) {
            int di = tap/3, dj = tap - di*3;
            half8 af0 = *(const half8*)(wbuf + (size_t)(tap*256 + lq*128 + wc*64 + l31)*16);
            half8 af1 = *(const half8*)(wbuf + (size_t)(tap*256 + lq*128 + wc*64 + 32 + l31)*16);
            int h0 = wh*64 + l31 + di - 1;
            half8 bf0 = *(const half8*)(xb + (size_t)(dj*512 + lq*256 + (h0 & 255))*8);
            half8 bf1 = *(const half8*)(xb + (size_t)(dj*512 + lq*256 + ((h0 + 32) & 255))*8);
            acc[0][0] = __builtin_amdgcn_mfma_f32_32x32x16_f16(af0, bf0, acc[0][0], 0, 0, 0);
            acc[0][1] = __builtin_amdgcn_mfma_f32_32x32x16_f16(af0, bf1, acc[0][1], 0, 0, 0);
            acc[1][0] = __builtin_amdgcn_mfma_f32_32x32x16_f16(af1, bf0, acc[1][0], 0, 0, 0);
            acc[1][1] = __builtin_amdgcn_mfma_f32_32x32x16_f16(af1, bf1, acc[1][1], 0, 0, 0);
        }
        __syncthreads();
    }

    float rs = rsqrtf(1.f + 1e-5f);
    if (OUT_F16) {
        f16* otile = (f16*)sbuf;           // [128][136], two h-phases
        f16* yout = (f16*)outp + ((size_t)(s*128 + w)*256)*128;
        #pragma unroll
        for (int ph = 0; ph < 2; ++ph) {
            __syncthreads();
            if ((wh >> 1) == ph) {
                #pragma unroll
                for (int ct = 0; ct < 2; ++ct) {
                    #pragma unroll
                    for (int ht = 0; ht < 2; ++ht) {
                        int hrow = (wh & 1)*64 + ht*32 + l31;
                        #pragma unroll
                        for (int rq = 0; rq < 4; ++rq) {
                            int cb = wc*64 + ct*32 + rq*8 + lq*4;
                            float4 g4 = *(const float4*)&bng[cb];
                            float4 b4 = *(const float4*)&bnb[cb];
                            half4_t v;
                            #pragma unroll
                            for (int e = 0; e < 4; ++e) {
                                float g = (&g4.x)[e], bb = (&b4.x)[e];
                                v[e] = (f16)fmaxf(acc[ct][ht][rq*4 + e]*g*rs + bb, 0.f);
                            }
                            *(half4_t*)&otile[hrow*136 + cb] = v;
                        }
                    }
                }
            }
            __syncthreads();
            {
                int hrow = tid >> 2, qc = tid & 3;
                const f16* srcT = &otile[hrow*136 + qc*32];
                f16* d = yout + (size_t)(ph*128 + hrow)*128 + qc*32;
                #pragma unroll
                for (int k = 0; k < 4; ++k)
                    *(float4*)(d + k*8) = *(const float4*)(srcT + k*8);
            }
        }
    } else {
        #pragma unroll
        for (int ct = 0; ct < 2; ++ct) {
            #pragma unroll
            for (int ht = 0; ht < 2; ++ht) {
                int hrow = wh*64 + ht*32 + l31;
                #pragma unroll
                for (int r = 0; r < 16; ++r) {
                    int co = wc*64 + ct*32 + (r & 3) + 8*(r >> 2) + 4*lq;
                    float v = fmaxf(acc[ct][ht][r]*bng[co]*rs + bnb[co], 0.f);
                    ((float*)outp)[((size_t)(s*128 + co)*128 + w)*256 + hrow] = v;
                }
            }
        }
    }
}

// ============================================================
extern "C" void kernel_launch(void* const* d_in, const int* in_sizes, int n_in,
                              void* d_out, int out_size, void* d_ws, size_t ws_size,
                              hipStream_t stream) {
    const float* x      = (const float*)d_in[0];
    const float* seidel = (const float*)d_in[1];
    const float* m1W1 = (const float*)d_in[2];
    const float* m1b1 = (const float*)d_in[3];
    const float* m1W2 = (const float*)d_in[4];
    const float* m1b2 = (const float*)d_in[5];
    const float* m2W1 = (const float*)d_in[6];
    const float* m2b1 = (const float*)d_in[7];
    const float* m2W2 = (const float*)d_in[8];
    const float* m2b2 = (const float*)d_in[9];
    const float* hw2  = (const float*)d_in[10];
    const float* hb2  = (const float*)d_in[11];
    const float* hw1  = (const float*)d_in[12];
    const float* hb1  = (const float*)d_in[13];
    const float* bn1g = (const float*)d_in[14];
    const float* bn1b = (const float*)d_in[15];
    const float* bn2g = (const float*)d_in[16];
    const float* bn2b = (const float*)d_in[17];
    float* outp = (float*)d_out;

    char* wsb = (char*)d_ws;
    // region map (lifetimes disjoint where overlapped):
    f16*   wtab = (f16*)wsb;                            // 0 .. 9437184
    f16*   y1t  = (f16*)(wsb + 9437184);                // 16777216
    f16*   xt   = (f16*)(wsb + 26214400);               // 16777216 (conv1 input)
    float* y2t  = (float*)(wsb + 26214400);             // 33554432 (overlays xt, born conv2)
    float4* zerop = (float4*)(wsb + 59768832);          // 64 B zero page
    // NOTE: hin/eout/hw1t now live OUTSIDE the xt region (prep writes xt
    // concurrently with embed/hw1t) — placed after zerop:
    float* hin  = (float*)(wsb + 59769856);             // 524288
    float* eout = (float*)(wsb + 60294144);             // 8192
    float* hw1t = (float*)(wsb + 60302336);             // 2359296 -> ends 62661632

    prep_kernel<<<1104, 256, 0, stream>>>(x, xt, zerop, seidel,
                                          m1W1, m1b1, m1W2, m1b2,
                                          m2W1, m2b1, m2W2, m2b2,
                                          eout, hw1, hw1t);
    embed_b3<<<64, 128, 0, stream>>>(eout, hw2, hb2, hin);
    hfin3_kernel<<<dim3(72, 16), 256, 0, stream>>>(hin, hw1t, hb1, wtab);
    conv_mfma14<1><<<256, 512, 0, stream>>>(xt, wtab, 0, bn1g, bn1b, (void*)y1t, zerop);
    conv_mfma14<0><<<256, 512, 0, stream>>>(y1t, wtab, 1, bn2g, bn2b, (void*)y2t, zerop);
    xpose_out<<<dim3(4, 8, 256), dim3(32, 8), 0, stream>>>(y2t, outp);
}